// Round 5
// baseline (237.388 us; speedup 1.0000x reference)
//
#include <hip/hip_runtime.h>
#include <hip/hip_bf16.h>
#include <math.h>

#define CC  128
#define RLD 136            // halves stride for [64][128] bf16 LDS tiles (272B)
#define VLD 72             // halves stride for vT / P buffers (144B)

typedef __attribute__((ext_vector_type(8))) short bf16x8;
typedef __attribute__((ext_vector_type(4))) float f32x4;

#define MFMA16(a, b, c) __builtin_amdgcn_mfma_f32_16x16x32_bf16((a), (b), (c), 0, 0, 0)

__device__ __forceinline__ unsigned short f2bf(float f) {
    unsigned int u = __float_as_uint(f);
    u += 0x7FFFu + ((u >> 16) & 1u);
    return (unsigned short)(u >> 16);
}
__device__ __forceinline__ float bf2f(unsigned short h) {
    return __uint_as_float(((unsigned int)h) << 16);
}
// pair convert -> v_cvt_pk_bf16_f32
__device__ __forceinline__ unsigned int f2bf2u(float lo, float hi) {
    __hip_bfloat162 h = __float22bfloat162_rn(make_float2(lo, hi));
    union { __hip_bfloat162 h2; unsigned int u; } cv; cv.h2 = h;
    return cv.u;
}
// branch-free gelu: Phi via Abramowitz-Stegun 26.2.17 (|err| < 7.5e-8)
__device__ __forceinline__ float gelu_fast(float v) {
    float ax  = fabsf(v);
    float t   = __builtin_amdgcn_rcpf(fmaf(0.2316419f, ax, 1.0f));
    float phi = 0.39894228f * __expf(-0.5f * ax * ax);
    float p   = t * fmaf(t, fmaf(t, fmaf(t, fmaf(t, 1.330274429f, -1.821255978f),
                                   1.781477937f), -0.356563782f), 0.319381530f);
    float cpos = fmaf(-phi, p, 1.0f);          // Phi(|v|)
    float c    = (v >= 0.f) ? cpos : 1.0f - cpos;
    return v * c;
}

// ---- weight pre-pack: fragment-major bf16 (scale folded in) ----
__global__ void pack_w(const float* __restrict__ src, unsigned short* __restrict__ dst,
                       int K, int N, int mode, float scale) {
    int i = blockIdx.x * 256 + threadIdx.x;
    if (i >= K * N) return;
    int j   = i & 7;
    int l   = (i >> 3) & 63;
    int tkt = i >> 9;
    int KT  = K >> 5;
    int nt  = tkt / KT;
    int kt  = tkt - nt * KT;
    int k   = kt * 32 + (l >> 4) * 8 + j;
    int n   = nt * 16 + (l & 15);
    float v = (mode == 0) ? src[k * N + n]
                          : src[(n >> 4) * (K * 16) + k * 16 + (n & 15)];
    dst[i] = f2bf(v * scale);
}

// packed-weight half offsets in d_ws
#define OQ  0
#define OKk 16384
#define OV  32768
#define OP  49152
#define O1  65536
#define O2  131072

// One block = 1 batch element (64 rows). 512 threads = 8 waves. ~70 KB LDS -> 2 blocks/CU.
__global__ __launch_bounds__(512, 4) void block_fused(
    const float* __restrict__ x,
    const unsigned short* __restrict__ wpk,
    const float* __restrict__ bp,
    const float* __restrict__ b1, const float* __restrict__ b2,
    const float* __restrict__ g1, const float* __restrict__ be1,
    const float* __restrict__ g2, const float* __restrict__ be2,
    float* __restrict__ out)
{
    __shared__ __align__(16) unsigned short A [9216];  // h -> P tiles -> h2 -> f1(odd)
    __shared__ __align__(16) unsigned short Bq[8704];  // q -> attn concat
    __shared__ __align__(16) unsigned short Ck[8704];  // k -> x2
    __shared__ __align__(16) unsigned short Vv[9216];  // vT -> f1(even)

    const int tid  = threadIdx.x;
    const int lane = tid & 63;
    const int wave = tid >> 6;
    const int l15  = lane & 15;
    const int lg   = lane >> 4;

    const float* xb = x   + (size_t)blockIdx.x * (64 * CC);
    float*       ob = out + (size_t)blockIdx.x * (64 * CC);

    // ---------------- LN1: x -> A (h, bf16); one-pass E[x^2] form ----------------
    {
        float ga = g1[lane], gb = g1[lane + 64], ba = be1[lane], bb = be1[lane + 64];
        for (int r = wave * 8; r < wave * 8 + 8; ++r) {
            float v0 = xb[r * CC + lane], v1 = xb[r * CC + lane + 64];
            float s = v0 + v1;
            float q = fmaf(v0, v0, v1 * v1);
            #pragma unroll
            for (int off = 32; off; off >>= 1) {   // interleaved independent butterflies
                s += __shfl_xor(s, off);
                q += __shfl_xor(q, off);
            }
            float mean = s * (1.0f / CC);
            float var  = fmaf(-mean, mean, q * (1.0f / CC));
            float rstd = __builtin_amdgcn_rsqf(var + 1e-5f);
            float d0 = v0 - mean, d1 = v1 - mean;
            unsigned int u = f2bf2u(fmaf(ga, d0 * rstd, ba), fmaf(gb, d1 * rstd, bb));
            A[r * RLD + lane]      = (unsigned short)u;
            A[r * RLD + lane + 64] = (unsigned short)(u >> 16);
        }
    }
    __syncthreads();

    const int rt  = wave >> 1;          // row tile 0..3 (16 rows each)
    const int cg  = wave & 1;           // column-group split
    const int row0 = rt * 16 + lg * 4;  // C-fragment write base row

    // ---------------- QKV: A(h) @ Wqkv -> Bq(q*0.25 folded), Ck(k), Vv(vT) ----------------
    {
        bf16x8 la[4];
        #pragma unroll
        for (int kt = 0; kt < 4; ++kt)
            la[kt] = *(const bf16x8*)&A[(rt * 16 + l15) * RLD + kt * 32 + lg * 8];

        #pragma unroll 1
        for (int ntl = 0; ntl < 12; ++ntl) {
            int nt = cg * 12 + ntl;                 // 0..23: 0-7 q, 8-15 k, 16-23 v
            int sec = nt >> 3, ntn = nt & 7;
            const unsigned short* wb = wpk + sec * 16384;
            f32x4 c = {0.f, 0.f, 0.f, 0.f};
            #pragma unroll
            for (int kt = 0; kt < 4; ++kt) {
                bf16x8 b = *(const bf16x8*)&wb[((ntn * 4 + kt) * 64 + lane) * 8];
                c = MFMA16(la[kt], b, c);
            }
            unsigned int u01 = f2bf2u(c[0], c[1]);
            unsigned int u23 = f2bf2u(c[2], c[3]);
            if (sec == 0) {
                int o = row0 * RLD + ntn * 16 + l15;
                Bq[o]           = (unsigned short)u01;
                Bq[o + RLD]     = (unsigned short)(u01 >> 16);
                Bq[o + 2 * RLD] = (unsigned short)u23;
                Bq[o + 3 * RLD] = (unsigned short)(u23 >> 16);
            } else if (sec == 1) {
                int o = row0 * RLD + ntn * 16 + l15;
                Ck[o]           = (unsigned short)u01;
                Ck[o + RLD]     = (unsigned short)(u01 >> 16);
                Ck[o + 2 * RLD] = (unsigned short)u23;
                Ck[o + 3 * RLD] = (unsigned short)(u23 >> 16);
            } else {   // v, transposed: rows adjacent -> one b64 store
                *(uint2*)&Vv[(ntn * 16 + l15) * VLD + row0] = make_uint2(u01, u23);
            }
        }
    }

    // prefetch proj's residual x values (hide HBM/L2 latency under attention)
    float xpre[16];
    #pragma unroll
    for (int ntl = 0; ntl < 4; ++ntl) {
        int col = (cg * 4 + ntl) * 16 + l15;
        #pragma unroll
        for (int r = 0; r < 4; ++r)
            xpre[ntl * 4 + r] = xb[(row0 + r) * CC + col];
    }
    __syncthreads();

    // ---------------- attention: wave = head ----------------
    {
        unsigned short* pw = A + wave * 16 * VLD;   // P tile [16][64] (overlays h, dead)
        const int hcol = wave * 16;
        f32x4 ocs[4];
        bf16x8 zf = {0, 0, 0, 0, 0, 0, 0, 0};

        #pragma unroll 1
        for (int mt = 0; mt < 4; ++mt) {
            // scores S = q @ k^T (K=16; lanes>=32 feed zeros); 0.25 scale pre-folded
            f32x4 sfr[4];
            #pragma unroll
            for (int st = 0; st < 4; ++st) sfr[st] = (f32x4){0.f, 0.f, 0.f, 0.f};
            bf16x8 aq = zf;
            if (lane < 32)
                aq = *(const bf16x8*)&Bq[(mt * 16 + l15) * RLD + hcol + lg * 8];
            #pragma unroll
            for (int st = 0; st < 4; ++st) {
                if (st <= mt) {
                    bf16x8 bk = zf;
                    if (lane < 32)
                        bk = *(const bf16x8*)&Ck[(st * 16 + l15) * RLD + hcol + lg * 8];
                    sfr[st] = MFMA16(aq, bk, sfr[st]);
                }
            }
            // causal softmax, deferred normalization (store raw e; scale after PV)
            float inv4[4];
            #pragma unroll
            for (int r = 0; r < 4; ++r) {
                float sv[4], e[4];
                float mx = -3.0e38f;
                #pragma unroll
                for (int st = 0; st < 4; ++st) {
                    if (st <= mt) {
                        float s = sfr[st][r];
                        if (st == mt) s = (l15 <= lg * 4 + r) ? s : -3.0e38f;
                        sv[st] = s;
                        mx = fmaxf(mx, s);
                    }
                }
                #pragma unroll
                for (int off = 1; off < 16; off <<= 1) mx = fmaxf(mx, __shfl_xor(mx, off));
                float sum = 0.f;
                #pragma unroll
                for (int st = 0; st < 4; ++st) {
                    if (st <= mt) { e[st] = __expf(sv[st] - mx); sum += e[st]; }
                }
                // stores go out while the sum butterfly runs
                int ro = (lg * 4 + r) * VLD + l15;
                #pragma unroll
                for (int st = 0; st < 4; st += 2) {
                    if (st + 1 <= mt) {
                        unsigned int u = f2bf2u(e[st], e[st + 1]);
                        pw[ro + st * 16]       = (unsigned short)u;
                        pw[ro + (st + 1) * 16] = (unsigned short)(u >> 16);
                    } else if (st <= mt) {
                        pw[ro + st * 16]       = f2bf(e[st]);
                        pw[ro + (st + 1) * 16] = 0;
                    }
                }
                #pragma unroll
                for (int off = 1; off < 16; off <<= 1) sum += __shfl_xor(sum, off);
                inv4[r] = __builtin_amdgcn_rcpf(sum);
            }
            // PV: only K-chunks with live columns
            f32x4 oc = {0.f, 0.f, 0.f, 0.f};
            #pragma unroll
            for (int kt = 0; kt < 2; ++kt) {
                if (kt <= (mt >> 1)) {
                    bf16x8 ap = *(const bf16x8*)&pw[l15 * VLD + kt * 32 + lg * 8];
                    bf16x8 bv = *(const bf16x8*)&Vv[(hcol + l15) * VLD + kt * 32 + lg * 8];
                    oc = MFMA16(ap, bv, oc);
                }
            }
            #pragma unroll
            for (int r = 0; r < 4; ++r) oc[r] *= inv4[r];   // deferred softmax norm
            ocs[mt] = oc;
        }
        __syncthreads();   // all waves done reading q (Bq) and k/v
        #pragma unroll
        for (int mt = 0; mt < 4; ++mt) {
            unsigned int u01 = f2bf2u(ocs[mt][0], ocs[mt][1]);
            unsigned int u23 = f2bf2u(ocs[mt][2], ocs[mt][3]);
            int o = (mt * 16 + lg * 4) * RLD + hcol + l15;
            Bq[o]           = (unsigned short)u01;
            Bq[o + RLD]     = (unsigned short)(u01 >> 16);
            Bq[o + 2 * RLD] = (unsigned short)u23;
            Bq[o + 3 * RLD] = (unsigned short)(u23 >> 16);
        }
    }
    __syncthreads();

    // ---------------- proj + residual: x2 = x + attn @ Wp + bp -> Ck ----------------
    {
        bf16x8 pa[4];
        #pragma unroll
        for (int kt = 0; kt < 4; ++kt)
            pa[kt] = *(const bf16x8*)&Bq[(rt * 16 + l15) * RLD + kt * 32 + lg * 8];
        #pragma unroll 1
        for (int ntl = 0; ntl < 4; ++ntl) {
            int nt = cg * 4 + ntl;
            f32x4 c = {0.f, 0.f, 0.f, 0.f};
            #pragma unroll
            for (int kt = 0; kt < 4; ++kt) {
                bf16x8 b = *(const bf16x8*)&wpk[OP + ((nt * 4 + kt) * 64 + lane) * 8];
                c = MFMA16(pa[kt], b, c);
            }
            int col = nt * 16 + l15;
            float bpv = bp[col];
            unsigned int u01 = f2bf2u(xpre[ntl * 4 + 0] + c[0] + bpv,
                                      xpre[ntl * 4 + 1] + c[1] + bpv);
            unsigned int u23 = f2bf2u(xpre[ntl * 4 + 2] + c[2] + bpv,
                                      xpre[ntl * 4 + 3] + c[3] + bpv);
            int o = row0 * RLD + col;
            Ck[o]           = (unsigned short)u01;
            Ck[o + RLD]     = (unsigned short)(u01 >> 16);
            Ck[o + 2 * RLD] = (unsigned short)u23;
            Ck[o + 3 * RLD] = (unsigned short)(u23 >> 16);
        }
    }
    __syncthreads();

    // ---------------- LN2: Ck(x2) -> A(h2); one-pass form ----------------
    {
        float ga = g2[lane], gb = g2[lane + 64], ba = be2[lane], bb = be2[lane + 64];
        for (int r = wave * 8; r < wave * 8 + 8; ++r) {
            float v0 = bf2f(Ck[r * RLD + lane]), v1 = bf2f(Ck[r * RLD + lane + 64]);
            float s = v0 + v1;
            float q = fmaf(v0, v0, v1 * v1);
            #pragma unroll
            for (int off = 32; off; off >>= 1) {
                s += __shfl_xor(s, off);
                q += __shfl_xor(q, off);
            }
            float mean = s * (1.0f / CC);
            float var  = fmaf(-mean, mean, q * (1.0f / CC));
            float rstd = __builtin_amdgcn_rsqf(var + 1e-5f);
            float d0 = v0 - mean, d1 = v1 - mean;
            unsigned int u = f2bf2u(fmaf(ga, d0 * rstd, ba), fmaf(gb, d1 * rstd, bb));
            A[r * RLD + lane]      = (unsigned short)u;
            A[r * RLD + lane + 64] = (unsigned short)(u >> 16);
        }
    }
    __syncthreads();

    // ---------------- FF: out = x2 + gelu(h2@W1+b1)@W2 + b2 ----------------
    // f1 ping-pongs between Vv (even jc) and A (odd jc): one barrier per jc,
    // FF1(jc+1) overlaps FF2(jc).
    {
        bf16x8 ha[4];
        #pragma unroll
        for (int kt = 0; kt < 4; ++kt)
            ha[kt] = *(const bf16x8*)&A[(rt * 16 + l15) * RLD + kt * 32 + lg * 8];
        f32x4 facc[4];
        #pragma unroll
        for (int n = 0; n < 4; ++n) facc[n] = (f32x4){0.f, 0.f, 0.f, 0.f};

        #pragma unroll 1
        for (int jc = 0; jc < 4; ++jc) {
            unsigned short* f1 = (jc & 1) ? A : Vv;
            // FF1 chunk: gelu(h2 @ W1[:, jc*128 : +128] + b1) -> f1
            #pragma unroll 1
            for (int ntl = 0; ntl < 4; ++ntl) {
                int ntg = jc * 8 + cg * 4 + ntl;
                f32x4 c = {0.f, 0.f, 0.f, 0.f};
                #pragma unroll
                for (int kt = 0; kt < 4; ++kt) {
                    bf16x8 b = *(const bf16x8*)&wpk[O1 + ((ntg * 4 + kt) * 64 + lane) * 8];
                    c = MFMA16(ha[kt], b, c);
                }
                float b1v = b1[ntg * 16 + l15];
                unsigned int u01 = f2bf2u(gelu_fast(c[0] + b1v), gelu_fast(c[1] + b1v));
                unsigned int u23 = f2bf2u(gelu_fast(c[2] + b1v), gelu_fast(c[3] + b1v));
                int o = row0 * RLD + (cg * 4 + ntl) * 16 + l15;
                f1[o]           = (unsigned short)u01;
                f1[o + RLD]     = (unsigned short)(u01 >> 16);
                f1[o + 2 * RLD] = (unsigned short)u23;
                f1[o + 3 * RLD] = (unsigned short)(u23 >> 16);
            }
            __syncthreads();
            // FF2 partial: facc += f1 @ W2[jc*128 : +128, cols]
            #pragma unroll 1
            for (int kt = 0; kt < 4; ++kt) {
                int ktg = jc * 4 + kt;
                bf16x8 a0 = *(const bf16x8*)&f1[(rt * 16 + l15) * RLD + kt * 32 + lg * 8];
                #pragma unroll
                for (int ntl = 0; ntl < 4; ++ntl) {
                    int nt = cg * 4 + ntl;
                    bf16x8 b = *(const bf16x8*)&wpk[O2 + ((nt * 16 + ktg) * 64 + lane) * 8];
                    facc[ntl] = MFMA16(a0, b, facc[ntl]);
                }
            }
            // no trailing barrier: next FF1 writes the OTHER buffer; by the time any
            // wave re-writes this one (jc+2), every wave has passed barrier(jc+1)
            // after having drained its FF2(jc) reads (data-dep before its own MFMAs).
        }

        // epilogue: out = x2 + ff + b2
        #pragma unroll
        for (int ntl = 0; ntl < 4; ++ntl) {
            int col = (cg * 4 + ntl) * 16 + l15;
            float b2v = b2[col];
            #pragma unroll
            for (int r = 0; r < 4; ++r)
                ob[(row0 + r) * CC + col] =
                    bf2f(Ck[(row0 + r) * RLD + col]) + facc[ntl][r] + b2v;
        }
    }
}

extern "C" void kernel_launch(void* const* d_in, const int* in_sizes, int n_in,
                              void* d_out, int out_size, void* d_ws, size_t ws_size,
                              hipStream_t stream) {
    (void)n_in; (void)out_size; (void)ws_size;
    const float* x   = (const float*)d_in[0];
    const float* wq  = (const float*)d_in[1];
    const float* wk  = (const float*)d_in[2];
    const float* wv  = (const float*)d_in[3];
    const float* wp  = (const float*)d_in[4];
    const float* bp  = (const float*)d_in[5];
    const float* w1  = (const float*)d_in[6];
    const float* b1  = (const float*)d_in[7];
    const float* w2  = (const float*)d_in[8];
    const float* b2  = (const float*)d_in[9];
    const float* g1  = (const float*)d_in[10];
    const float* be1 = (const float*)d_in[11];
    const float* g2  = (const float*)d_in[12];
    const float* be2 = (const float*)d_in[13];

    unsigned short* ws16 = (unsigned short*)d_ws;
    pack_w<<<64,  256, 0, stream>>>(wq, ws16 + OQ,  128, 128, 1, 0.25f);  // HD^-0.5 folded
    pack_w<<<64,  256, 0, stream>>>(wk, ws16 + OKk, 128, 128, 1, 1.0f);
    pack_w<<<64,  256, 0, stream>>>(wv, ws16 + OV,  128, 128, 1, 1.0f);
    pack_w<<<64,  256, 0, stream>>>(wp, ws16 + OP,  128, 128, 0, 1.0f);
    pack_w<<<256, 256, 0, stream>>>(w1, ws16 + O1,  128, 512, 0, 1.0f);
    pack_w<<<256, 256, 0, stream>>>(w2, ws16 + O2,  512, 128, 0, 1.0f);

    int nblk = in_sizes[0] / (64 * CC);   // one block per batch element
    block_fused<<<dim3(nblk), dim3(512), 0, stream>>>(
        x, ws16, bp, b1, b2, g1, be1, g2, be2, (float*)d_out);
}

// Round 6
// 216.282 us; speedup vs baseline: 1.0976x; 1.0976x over previous
//
#include <hip/hip_runtime.h>
#include <hip/hip_bf16.h>
#include <math.h>

#define CC  128
#define RLD 136            // halves stride for [64][128] bf16 LDS tiles (272B)
#define VLD 72             // halves stride for vT / P buffers (144B)

typedef __attribute__((ext_vector_type(8))) short bf16x8;
typedef __attribute__((ext_vector_type(4))) float f32x4;

#define MFMA16(a, b, c) __builtin_amdgcn_mfma_f32_16x16x32_bf16((a), (b), (c), 0, 0, 0)

__device__ __forceinline__ unsigned short f2bf(float f) {
    unsigned int u = __float_as_uint(f);
    u += 0x7FFFu + ((u >> 16) & 1u);
    return (unsigned short)(u >> 16);
}
__device__ __forceinline__ float bf2f(unsigned short h) {
    return __uint_as_float(((unsigned int)h) << 16);
}
// pair convert -> v_cvt_pk_bf16_f32
__device__ __forceinline__ unsigned int f2bf2u(float lo, float hi) {
    __hip_bfloat162 h = __float22bfloat162_rn(make_float2(lo, hi));
    union { __hip_bfloat162 h2; unsigned int u; } cv; cv.h2 = h;
    return cv.u;
}
// branch-free gelu: Phi via Abramowitz-Stegun 26.2.17 (|err| < 7.5e-8)
__device__ __forceinline__ float gelu_fast(float v) {
    float ax  = fabsf(v);
    float t   = __builtin_amdgcn_rcpf(fmaf(0.2316419f, ax, 1.0f));
    float phi = 0.39894228f * __expf(-0.5f * ax * ax);
    float p   = t * fmaf(t, fmaf(t, fmaf(t, fmaf(t, 1.330274429f, -1.821255978f),
                                   1.781477937f), -0.356563782f), 0.319381530f);
    float cpos = fmaf(-phi, p, 1.0f);          // Phi(|v|)
    float c    = (v >= 0.f) ? cpos : 1.0f - cpos;
    return v * c;
}

// ---- weight pre-pack: fragment-major bf16 (scale folded in) ----
__global__ void pack_w(const float* __restrict__ src, unsigned short* __restrict__ dst,
                       int K, int N, int mode, float scale) {
    int i = blockIdx.x * 256 + threadIdx.x;
    if (i >= K * N) return;
    int j   = i & 7;
    int l   = (i >> 3) & 63;
    int tkt = i >> 9;
    int KT  = K >> 5;
    int nt  = tkt / KT;
    int kt  = tkt - nt * KT;
    int k   = kt * 32 + (l >> 4) * 8 + j;
    int n   = nt * 16 + (l & 15);
    float v = (mode == 0) ? src[k * N + n]
                          : src[(n >> 4) * (K * 16) + k * 16 + (n & 15)];
    dst[i] = f2bf(v * scale);
}

// packed-weight half offsets in d_ws
#define OQ  0
#define OKk 16384
#define OV  32768
#define OP  49152
#define O1  65536
#define O2  131072

// One block = 1 batch element (64 rows). 512 threads = 8 waves. ~70 KB LDS -> 2 blocks/CU.
__global__ __launch_bounds__(512, 4) void block_fused(
    const float* __restrict__ x,
    const unsigned short* __restrict__ wpk,
    const float* __restrict__ bp,
    const float* __restrict__ b1, const float* __restrict__ b2,
    const float* __restrict__ g1, const float* __restrict__ be1,
    const float* __restrict__ g2, const float* __restrict__ be2,
    float* __restrict__ out)
{
    __shared__ __align__(16) unsigned short A [9216];  // h -> P tiles -> h2 -> f1(odd)
    __shared__ __align__(16) unsigned short Bq[8704];  // q -> attn concat
    __shared__ __align__(16) unsigned short Ck[8704];  // k -> x2
    __shared__ __align__(16) unsigned short Vv[9216];  // vT -> f1(even)

    const int tid  = threadIdx.x;
    const int lane = tid & 63;
    const int wave = tid >> 6;
    const int l15  = lane & 15;
    const int lg   = lane >> 4;

    const float* xb = x   + (size_t)blockIdx.x * (64 * CC);
    float*       ob = out + (size_t)blockIdx.x * (64 * CC);

    // ---------------- LN1: x -> A (h, bf16); one-pass E[x^2] form ----------------
    {
        float ga = g1[lane], gb = g1[lane + 64], ba = be1[lane], bb = be1[lane + 64];
        for (int r = wave * 8; r < wave * 8 + 8; ++r) {
            float v0 = xb[r * CC + lane], v1 = xb[r * CC + lane + 64];
            float s = v0 + v1;
            float q = fmaf(v0, v0, v1 * v1);
            #pragma unroll
            for (int off = 32; off; off >>= 1) {   // interleaved independent butterflies
                s += __shfl_xor(s, off);
                q += __shfl_xor(q, off);
            }
            float mean = s * (1.0f / CC);
            float var  = fmaf(-mean, mean, q * (1.0f / CC));
            float rstd = __builtin_amdgcn_rsqf(var + 1e-5f);
            float d0 = v0 - mean, d1 = v1 - mean;
            unsigned int u = f2bf2u(fmaf(ga, d0 * rstd, ba), fmaf(gb, d1 * rstd, bb));
            A[r * RLD + lane]      = (unsigned short)u;
            A[r * RLD + lane + 64] = (unsigned short)(u >> 16);
        }
    }
    __syncthreads();

    const int rt  = wave >> 1;          // row tile 0..3 (16 rows each)
    const int cg  = wave & 1;           // column-group split
    const int row0 = rt * 16 + lg * 4;  // C-fragment write base row

    // ---------------- QKV: A(h) @ Wqkv -> Bq(q*0.25 folded), Ck(k), Vv(vT) ----------------
    {
        bf16x8 la[4];
        #pragma unroll
        for (int kt = 0; kt < 4; ++kt)
            la[kt] = *(const bf16x8*)&A[(rt * 16 + l15) * RLD + kt * 32 + lg * 8];

        #pragma unroll 1
        for (int ntl = 0; ntl < 12; ++ntl) {
            int nt = cg * 12 + ntl;                 // 0..23: 0-7 q, 8-15 k, 16-23 v
            int sec = nt >> 3, ntn = nt & 7;
            const unsigned short* wb = wpk + sec * 16384;
            f32x4 c = {0.f, 0.f, 0.f, 0.f};
            #pragma unroll
            for (int kt = 0; kt < 4; ++kt) {
                bf16x8 b = *(const bf16x8*)&wb[((ntn * 4 + kt) * 64 + lane) * 8];
                c = MFMA16(la[kt], b, c);
            }
            unsigned int u01 = f2bf2u(c[0], c[1]);
            unsigned int u23 = f2bf2u(c[2], c[3]);
            if (sec == 0) {
                int o = row0 * RLD + ntn * 16 + l15;
                Bq[o]           = (unsigned short)u01;
                Bq[o + RLD]     = (unsigned short)(u01 >> 16);
                Bq[o + 2 * RLD] = (unsigned short)u23;
                Bq[o + 3 * RLD] = (unsigned short)(u23 >> 16);
            } else if (sec == 1) {
                int o = row0 * RLD + ntn * 16 + l15;
                Ck[o]           = (unsigned short)u01;
                Ck[o + RLD]     = (unsigned short)(u01 >> 16);
                Ck[o + 2 * RLD] = (unsigned short)u23;
                Ck[o + 3 * RLD] = (unsigned short)(u23 >> 16);
            } else {   // v, transposed: rows adjacent -> one b64 store
                *(uint2*)&Vv[(ntn * 16 + l15) * VLD + row0] = make_uint2(u01, u23);
            }
        }
    }

    // prefetch proj's residual x (hide latency under attention); all indices
    // compile-time constant -> stays in VGPRs (NOT scratch)
    float xpre[16];
    #pragma unroll
    for (int ntl = 0; ntl < 4; ++ntl) {
        int col = (cg * 4 + ntl) * 16 + l15;
        #pragma unroll
        for (int r = 0; r < 4; ++r)
            xpre[ntl * 4 + r] = xb[(row0 + r) * CC + col];
    }
    __syncthreads();

    // ---------------- attention: wave = head ----------------
    {
        unsigned short* pw = A + wave * 16 * VLD;   // P tile [16][64] (overlays h, dead)
        const int hcol = wave * 16;
        f32x4 ocs[4];
        bf16x8 zf = {0, 0, 0, 0, 0, 0, 0, 0};

        #pragma unroll 1
        for (int mt = 0; mt < 4; ++mt) {
            // scores S = q @ k^T (K=16; lanes>=32 feed zeros); 0.25 scale pre-folded
            f32x4 sfr[4];
            #pragma unroll
            for (int st = 0; st < 4; ++st) sfr[st] = (f32x4){0.f, 0.f, 0.f, 0.f};
            bf16x8 aq = zf;
            if (lane < 32)
                aq = *(const bf16x8*)&Bq[(mt * 16 + l15) * RLD + hcol + lg * 8];
            #pragma unroll
            for (int st = 0; st < 4; ++st) {
                if (st <= mt) {
                    bf16x8 bk = zf;
                    if (lane < 32)
                        bk = *(const bf16x8*)&Ck[(st * 16 + l15) * RLD + hcol + lg * 8];
                    sfr[st] = MFMA16(aq, bk, sfr[st]);
                }
            }
            // causal softmax, deferred normalization (store raw e; scale after PV)
            float inv4[4];
            #pragma unroll
            for (int r = 0; r < 4; ++r) {
                float sv[4], e[4];
                float mx = -3.0e38f;
                #pragma unroll
                for (int st = 0; st < 4; ++st) {
                    if (st <= mt) {
                        float s = sfr[st][r];
                        if (st == mt) s = (l15 <= lg * 4 + r) ? s : -3.0e38f;
                        sv[st] = s;
                        mx = fmaxf(mx, s);
                    }
                }
                #pragma unroll
                for (int off = 1; off < 16; off <<= 1) mx = fmaxf(mx, __shfl_xor(mx, off));
                float sum = 0.f;
                #pragma unroll
                for (int st = 0; st < 4; ++st) {
                    if (st <= mt) { e[st] = __expf(sv[st] - mx); sum += e[st]; }
                }
                // stores go out while the sum butterfly runs
                int ro = (lg * 4 + r) * VLD + l15;
                #pragma unroll
                for (int st = 0; st < 4; st += 2) {
                    if (st + 1 <= mt) {
                        unsigned int u = f2bf2u(e[st], e[st + 1]);
                        pw[ro + st * 16]       = (unsigned short)u;
                        pw[ro + (st + 1) * 16] = (unsigned short)(u >> 16);
                    } else if (st <= mt) {
                        pw[ro + st * 16]       = f2bf(e[st]);
                        pw[ro + (st + 1) * 16] = 0;
                    }
                }
                #pragma unroll
                for (int off = 1; off < 16; off <<= 1) sum += __shfl_xor(sum, off);
                inv4[r] = __builtin_amdgcn_rcpf(sum);
            }
            // PV: only K-chunks with live columns
            f32x4 oc = {0.f, 0.f, 0.f, 0.f};
            #pragma unroll
            for (int kt = 0; kt < 2; ++kt) {
                if (kt <= (mt >> 1)) {
                    bf16x8 ap = *(const bf16x8*)&pw[l15 * VLD + kt * 32 + lg * 8];
                    bf16x8 bv = *(const bf16x8*)&Vv[(hcol + l15) * VLD + kt * 32 + lg * 8];
                    oc = MFMA16(ap, bv, oc);
                }
            }
            #pragma unroll
            for (int r = 0; r < 4; ++r) oc[r] *= inv4[r];   // deferred softmax norm
            ocs[mt] = oc;
        }
        __syncthreads();   // all waves done reading q (Bq) and k/v
        #pragma unroll
        for (int mt = 0; mt < 4; ++mt) {
            unsigned int u01 = f2bf2u(ocs[mt][0], ocs[mt][1]);
            unsigned int u23 = f2bf2u(ocs[mt][2], ocs[mt][3]);
            int o = (mt * 16 + lg * 4) * RLD + hcol + l15;
            Bq[o]           = (unsigned short)u01;
            Bq[o + RLD]     = (unsigned short)(u01 >> 16);
            Bq[o + 2 * RLD] = (unsigned short)u23;
            Bq[o + 3 * RLD] = (unsigned short)(u23 >> 16);
        }
    }
    __syncthreads();

    // ---------------- proj + residual: x2 = x + attn @ Wp + bp -> Ck ----------------
    // FULLY unrolled so xpre[] indices are compile-time constants (rule #20)
    {
        bf16x8 pa[4];
        #pragma unroll
        for (int kt = 0; kt < 4; ++kt)
            pa[kt] = *(const bf16x8*)&Bq[(rt * 16 + l15) * RLD + kt * 32 + lg * 8];
        #pragma unroll
        for (int ntl = 0; ntl < 4; ++ntl) {
            int nt = cg * 4 + ntl;
            f32x4 c = {0.f, 0.f, 0.f, 0.f};
            #pragma unroll
            for (int kt = 0; kt < 4; ++kt) {
                bf16x8 b = *(const bf16x8*)&wpk[OP + ((nt * 4 + kt) * 64 + lane) * 8];
                c = MFMA16(pa[kt], b, c);
            }
            int col = nt * 16 + l15;
            float bpv = bp[col];
            unsigned int u01 = f2bf2u(xpre[ntl * 4 + 0] + c[0] + bpv,
                                      xpre[ntl * 4 + 1] + c[1] + bpv);
            unsigned int u23 = f2bf2u(xpre[ntl * 4 + 2] + c[2] + bpv,
                                      xpre[ntl * 4 + 3] + c[3] + bpv);
            int o = row0 * RLD + col;
            Ck[o]           = (unsigned short)u01;
            Ck[o + RLD]     = (unsigned short)(u01 >> 16);
            Ck[o + 2 * RLD] = (unsigned short)u23;
            Ck[o + 3 * RLD] = (unsigned short)(u23 >> 16);
        }
    }
    __syncthreads();

    // ---------------- LN2: Ck(x2) -> A(h2); one-pass form ----------------
    {
        float ga = g2[lane], gb = g2[lane + 64], ba = be2[lane], bb = be2[lane + 64];
        for (int r = wave * 8; r < wave * 8 + 8; ++r) {
            float v0 = bf2f(Ck[r * RLD + lane]), v1 = bf2f(Ck[r * RLD + lane + 64]);
            float s = v0 + v1;
            float q = fmaf(v0, v0, v1 * v1);
            #pragma unroll
            for (int off = 32; off; off >>= 1) {
                s += __shfl_xor(s, off);
                q += __shfl_xor(q, off);
            }
            float mean = s * (1.0f / CC);
            float var  = fmaf(-mean, mean, q * (1.0f / CC));
            float rstd = __builtin_amdgcn_rsqf(var + 1e-5f);
            float d0 = v0 - mean, d1 = v1 - mean;
            unsigned int u = f2bf2u(fmaf(ga, d0 * rstd, ba), fmaf(gb, d1 * rstd, bb));
            A[r * RLD + lane]      = (unsigned short)u;
            A[r * RLD + lane + 64] = (unsigned short)(u >> 16);
        }
    }
    __syncthreads();

    // ---------------- FF: out = x2 + gelu(h2@W1+b1)@W2 + b2 ----------------
    // f1 ping-pongs between Vv (even jc) and A (odd jc): one barrier per jc,
    // FF1(jc+1) overlaps FF2(jc).
    {
        bf16x8 ha[4];
        #pragma unroll
        for (int kt = 0; kt < 4; ++kt)
            ha[kt] = *(const bf16x8*)&A[(rt * 16 + l15) * RLD + kt * 32 + lg * 8];
        f32x4 facc[4];
        #pragma unroll
        for (int n = 0; n < 4; ++n) facc[n] = (f32x4){0.f, 0.f, 0.f, 0.f};

        #pragma unroll 1
        for (int jc = 0; jc < 4; ++jc) {
            unsigned short* f1 = (jc & 1) ? A : Vv;
            // FF1 chunk: gelu(h2 @ W1[:, jc*128 : +128] + b1) -> f1
            #pragma unroll 1
            for (int ntl = 0; ntl < 4; ++ntl) {
                int ntg = jc * 8 + cg * 4 + ntl;
                f32x4 c = {0.f, 0.f, 0.f, 0.f};
                #pragma unroll
                for (int kt = 0; kt < 4; ++kt) {
                    bf16x8 b = *(const bf16x8*)&wpk[O1 + ((ntg * 4 + kt) * 64 + lane) * 8];
                    c = MFMA16(ha[kt], b, c);
                }
                float b1v = b1[ntg * 16 + l15];
                unsigned int u01 = f2bf2u(gelu_fast(c[0] + b1v), gelu_fast(c[1] + b1v));
                unsigned int u23 = f2bf2u(gelu_fast(c[2] + b1v), gelu_fast(c[3] + b1v));
                int o = row0 * RLD + (cg * 4 + ntl) * 16 + l15;
                f1[o]           = (unsigned short)u01;
                f1[o + RLD]     = (unsigned short)(u01 >> 16);
                f1[o + 2 * RLD] = (unsigned short)u23;
                f1[o + 3 * RLD] = (unsigned short)(u23 >> 16);
            }
            __syncthreads();
            // FF2 partial: facc += f1 @ W2[jc*128 : +128, cols]
            #pragma unroll 1
            for (int kt = 0; kt < 4; ++kt) {
                int ktg = jc * 4 + kt;
                bf16x8 a0 = *(const bf16x8*)&f1[(rt * 16 + l15) * RLD + kt * 32 + lg * 8];
                #pragma unroll
                for (int ntl = 0; ntl < 4; ++ntl) {
                    int nt = cg * 4 + ntl;
                    bf16x8 b = *(const bf16x8*)&wpk[O2 + ((nt * 16 + ktg) * 64 + lane) * 8];
                    facc[ntl] = MFMA16(a0, b, facc[ntl]);
                }
            }
            // no trailing barrier: next FF1 writes the OTHER buffer; by the time any
            // wave re-writes this one (jc+2), every wave has passed barrier(jc+1)
            // after having drained its FF2(jc) reads (data-dep before its own MFMAs).
        }

        // epilogue: out = x2 + ff + b2
        #pragma unroll
        for (int ntl = 0; ntl < 4; ++ntl) {
            int col = (cg * 4 + ntl) * 16 + l15;
            float b2v = b2[col];
            #pragma unroll
            for (int r = 0; r < 4; ++r)
                ob[(row0 + r) * CC + col] =
                    bf2f(Ck[(row0 + r) * RLD + col]) + facc[ntl][r] + b2v;
        }
    }
}

extern "C" void kernel_launch(void* const* d_in, const int* in_sizes, int n_in,
                              void* d_out, int out_size, void* d_ws, size_t ws_size,
                              hipStream_t stream) {
    (void)n_in; (void)out_size; (void)ws_size;
    const float* x   = (const float*)d_in[0];
    const float* wq  = (const float*)d_in[1];
    const float* wk  = (const float*)d_in[2];
    const float* wv  = (const float*)d_in[3];
    const float* wp  = (const float*)d_in[4];
    const float* bp  = (const float*)d_in[5];
    const float* w1  = (const float*)d_in[6];
    const float* b1  = (const float*)d_in[7];
    const float* w2  = (const float*)d_in[8];
    const float* b2  = (const float*)d_in[9];
    const float* g1  = (const float*)d_in[10];
    const float* be1 = (const float*)d_in[11];
    const float* g2  = (const float*)d_in[12];
    const float* be2 = (const float*)d_in[13];

    unsigned short* ws16 = (unsigned short*)d_ws;
    pack_w<<<64,  256, 0, stream>>>(wq, ws16 + OQ,  128, 128, 1, 0.25f);  // HD^-0.5 folded
    pack_w<<<64,  256, 0, stream>>>(wk, ws16 + OKk, 128, 128, 1, 1.0f);
    pack_w<<<64,  256, 0, stream>>>(wv, ws16 + OV,  128, 128, 1, 1.0f);
    pack_w<<<64,  256, 0, stream>>>(wp, ws16 + OP,  128, 128, 0, 1.0f);
    pack_w<<<256, 256, 0, stream>>>(w1, ws16 + O1,  128, 512, 0, 1.0f);
    pack_w<<<256, 256, 0, stream>>>(w2, ws16 + O2,  512, 128, 0, 1.0f);

    int nblk = in_sizes[0] / (64 * CC);   // one block per batch element
    block_fused<<<dim3(nblk), dim3(512), 0, stream>>>(
        x, ws16, bp, b1, b2, g1, be1, g2, be2, (float*)d_out);
}